// Round 1
// baseline (533.483 us; speedup 1.0000x reference)
//
#include <hip/hip_runtime.h>
#include <hip/hip_bf16.h>

#define NB 256
#define DD 65536
#define NN 41
#define GG 2048
#define OO 256
#define NO 10496
#define EE 512
#define NEG_SLOPE 0.2f

typedef __attribute__((ext_vector_type(8))) short bf16x8;
typedef __attribute__((ext_vector_type(4))) float f32x4;
typedef unsigned int u32;

// ---- transpose + fp32->bf16 cast: src[z][K][Oc] -> dst[z][Oc][K] ----
__global__ __launch_bounds__(256) void transpose_cast_k(const float* __restrict__ src,
                                                        __hip_bfloat16* __restrict__ dst,
                                                        int K, int Oc) {
    __shared__ float tile[32][33];
    size_t slab = (size_t)blockIdx.z * K * Oc;
    int k0 = blockIdx.y * 32, o0 = blockIdx.x * 32;
    int tx = threadIdx.x & 31, ty = threadIdx.x >> 5;  // ty 0..7
    const float* s = src + slab;
#pragma unroll
    for (int i = 0; i < 4; ++i)
        tile[ty + 8 * i][tx] = s[(size_t)(k0 + ty + 8 * i) * Oc + o0 + tx];
    __syncthreads();
    __hip_bfloat16* d = dst + slab;
    int o = threadIdx.x >> 4;   // 0..15
    int kp = threadIdx.x & 15;  // k pair
#pragma unroll
    for (int i2 = 0; i2 < 2; ++i2) {
        int oo = o + 16 * i2;
        __hip_bfloat162 p;
        p.x = __float2bfloat16(tile[2 * kp][oo]);
        p.y = __float2bfloat16(tile[2 * kp + 1][oo]);
        *(__hip_bfloat162*)&d[(size_t)(o0 + oo) * K + k0 + 2 * kp] = p;
    }
}

// ---- gather + cast: g[n][b][k] = bf16(x[b][idx[n][k]]) ----
// 128 blocks, each handles rows b and b+128 sequentially (keeps one 256 KiB
// x-row hot per block; 16 blocks/XCD * 256 KiB = 4 MiB ~ L2)
__global__ __launch_bounds__(256) void gather_cast_k(const float* __restrict__ x,
                                                     const int* __restrict__ idx,
                                                     __hip_bfloat16* __restrict__ g) {
#pragma unroll
    for (int rb = 0; rb < 2; ++rb) {
        int row = blockIdx.x + rb * 128;
        const float* xr = x + (size_t)row * DD;
        for (int e = threadIdx.x; e < NN * (GG / 2); e += 256) {
            int n = e >> 10;          // GG/2 = 1024
            int kp = e & 1023;
            int i0 = idx[n * GG + 2 * kp];
            int i1 = idx[n * GG + 2 * kp + 1];
            __hip_bfloat162 p;
            p.x = __float2bfloat16(xr[i0]);
            p.y = __float2bfloat16(xr[i1]);
            *(__hip_bfloat162*)&g[((size_t)n * NB + row) * GG + 2 * kp] = p;
        }
    }
}

// ---- GEMM1: per n, h[b][n*OO+o] = bf16(sum_k g[n][b][k]*Wt[n][o][k] + bias[n][o])
// grid 164 = 41 n * 2 mtile * 2 ntile; block 256 thr = 4 waves; tile 128x128, BK=32
__global__ __launch_bounds__(256) void gemm1_k(const __hip_bfloat16* __restrict__ g,
                                               const __hip_bfloat16* __restrict__ Wt,
                                               const float* __restrict__ bias,
                                               __hip_bfloat16* __restrict__ h) {
    int bid = blockIdx.x;
    int n = bid >> 2;
    int m0 = ((bid >> 1) & 1) * 128;
    int o0 = (bid & 1) * 128;
    const u32* srcA = (const u32*)(g + ((size_t)n * NB + m0) * GG);
    const u32* srcB = (const u32*)(Wt + ((size_t)n * OO + o0) * GG);
    __shared__ __hip_bfloat16 lA[128 * 32];
    __shared__ __hip_bfloat16 lB[128 * 32];
    int t = threadIdx.x;
    int lane = t & 63, w = t >> 6;
    int mw = (w >> 1) * 64, nw = (w & 1) * 64;
    int lrow = lane & 15, quad = lane >> 4;
    f32x4 acc[4][4] = {};

    for (int k0 = 0; k0 < GG; k0 += 32) {
        __syncthreads();
        int kw = k0 >> 1;  // uint offset
#pragma unroll
        for (int i = 0; i < 8; ++i) {
            int u = t + 256 * i;
            int r = u >> 4, kk = u & 15;
            ((u32*)lA)[r * 16 + kk] = srcA[(size_t)r * (GG / 2) + kw + kk];
        }
#pragma unroll
        for (int i = 0; i < 8; ++i) {
            int u = t + 256 * i;
            int r = u >> 4, kk = u & 15;
            ((u32*)lB)[r * 16 + kk] = srcB[(size_t)r * (GG / 2) + kw + kk];
        }
        __syncthreads();
        bf16x8 af[4];
#pragma unroll
        for (int fm = 0; fm < 4; ++fm)
            af[fm] = *(const bf16x8*)&lA[(mw + fm * 16 + lrow) * 32 + quad * 8];
#pragma unroll
        for (int fn = 0; fn < 4; ++fn) {
            bf16x8 bfr = *(const bf16x8*)&lB[(nw + fn * 16 + lrow) * 32 + quad * 8];
#pragma unroll
            for (int fm = 0; fm < 4; ++fm)
                acc[fm][fn] = __builtin_amdgcn_mfma_f32_16x16x32_bf16(af[fm], bfr, acc[fm][fn], 0, 0, 0);
        }
    }
    // epilogue: C/D layout col=lane&15, row=quad*4+reg
#pragma unroll
    for (int fm = 0; fm < 4; ++fm) {
#pragma unroll
        for (int fn = 0; fn < 4; ++fn) {
            int col = o0 + nw + fn * 16 + lrow;  // global o
            float bv = bias[n * OO + col];
#pragma unroll
            for (int r = 0; r < 4; ++r) {
                int row = m0 + mw + fm * 16 + quad * 4 + r;  // global b
                h[(size_t)row * NO + n * OO + col] = __float2bfloat16(acc[fm][fn][r] + bv);
            }
        }
    }
}

// ---- GEMM2 split-K: part[s][b][e] = sum_{k in chunk s} h[b][k]*W3t[e][k]
// grid 328 = 8 etiles * 41 ksplits; block 256 thr; tile 256x64, Kchunk=256, BK=32
__global__ __launch_bounds__(256) void gemm2_k(const __hip_bfloat16* __restrict__ h,
                                               const __hip_bfloat16* __restrict__ W3t,
                                               float* __restrict__ part) {
    int e0 = (blockIdx.x & 7) * 64;
    int s = blockIdx.x >> 3;  // 0..40
    const u32* srcA = (const u32*)h;
    const u32* srcB = (const u32*)(W3t + (size_t)e0 * NO);
    __shared__ __hip_bfloat16 lA[256 * 32];
    __shared__ __hip_bfloat16 lB[64 * 32];
    int t = threadIdx.x;
    int lane = t & 63, w = t >> 6;
    int lrow = lane & 15, quad = lane >> 4;
    f32x4 acc[4][4] = {};

    for (int k0 = s * 256; k0 < s * 256 + 256; k0 += 32) {
        __syncthreads();
        int kw = k0 >> 1;
#pragma unroll
        for (int i = 0; i < 16; ++i) {
            int u = t + 256 * i;
            int r = u >> 4, kk = u & 15;
            ((u32*)lA)[r * 16 + kk] = srcA[(size_t)r * (NO / 2) + kw + kk];
        }
#pragma unroll
        for (int i = 0; i < 4; ++i) {
            int u = t + 256 * i;
            int r = u >> 4, kk = u & 15;
            ((u32*)lB)[r * 16 + kk] = srcB[(size_t)r * (NO / 2) + kw + kk];
        }
        __syncthreads();
        bf16x8 af[4];
#pragma unroll
        for (int fm = 0; fm < 4; ++fm)
            af[fm] = *(const bf16x8*)&lA[(w * 64 + fm * 16 + lrow) * 32 + quad * 8];
#pragma unroll
        for (int fn = 0; fn < 4; ++fn) {
            bf16x8 bfr = *(const bf16x8*)&lB[(fn * 16 + lrow) * 32 + quad * 8];
#pragma unroll
            for (int fm = 0; fm < 4; ++fm)
                acc[fm][fn] = __builtin_amdgcn_mfma_f32_16x16x32_bf16(af[fm], bfr, acc[fm][fn], 0, 0, 0);
        }
    }
#pragma unroll
    for (int fm = 0; fm < 4; ++fm) {
#pragma unroll
        for (int fn = 0; fn < 4; ++fn) {
            int e = e0 + fn * 16 + lrow;
#pragma unroll
            for (int r = 0; r < 4; ++r) {
                int row = w * 64 + fm * 16 + quad * 4 + r;
                part[((size_t)s * NB + row) * EE + e] = acc[fm][fn][r];
            }
        }
    }
}

// ---- reduce partials + bias + leaky relu ----
__global__ __launch_bounds__(256) void reduce_k(const float* __restrict__ part,
                                                const float* __restrict__ b3,
                                                float* __restrict__ out) {
    int j = blockIdx.x * 256 + threadIdx.x;  // float4 index over 256*512
    float4 a = make_float4(0.f, 0.f, 0.f, 0.f);
    for (int s = 0; s < NN; ++s) {
        float4 v = ((const float4*)part)[(size_t)s * (NB * EE / 4) + j];
        a.x += v.x; a.y += v.y; a.z += v.z; a.w += v.w;
    }
    float4 bv = ((const float4*)b3)[j & 127];
    a.x += bv.x; a.y += bv.y; a.z += bv.z; a.w += bv.w;
    a.x = a.x >= 0.f ? a.x : NEG_SLOPE * a.x;
    a.y = a.y >= 0.f ? a.y : NEG_SLOPE * a.y;
    a.z = a.z >= 0.f ? a.z : NEG_SLOPE * a.z;
    a.w = a.w >= 0.f ? a.w : NEG_SLOPE * a.w;
    ((float4*)out)[j] = a;
}

extern "C" void kernel_launch(void* const* d_in, const int* in_sizes, int n_in,
                              void* d_out, int out_size, void* d_ws, size_t ws_size,
                              hipStream_t stream) {
    const float* x = (const float*)d_in[0];
    const int* idx = (const int*)d_in[1];
    const float* W = (const float*)d_in[2];
    const float* bias = (const float*)d_in[3];
    const float* W3 = (const float*)d_in[4];
    const float* b3 = (const float*)d_in[5];
    float* out = (float*)d_out;

    char* ws = (char*)d_ws;
    const size_t g_off = 0;
    const size_t g_sz = (size_t)NN * NB * GG * 2;          // 42,991,616
    const size_t wt_off = g_off + g_sz;
    const size_t wt_sz = (size_t)NN * GG * OO * 2;         // 42,991,616
    const size_t w3t_off = wt_off + wt_sz;
    const size_t w3t_sz = (size_t)NO * EE * 2;             // 10,747,904
    const size_t h_off = w3t_off + w3t_sz;
    const size_t h_sz = (size_t)NB * NO * 2;               // 5,373,952
    const size_t part_off = h_off + h_sz;

    __hip_bfloat16* g = (__hip_bfloat16*)(ws + g_off);
    __hip_bfloat16* Wt = (__hip_bfloat16*)(ws + wt_off);
    __hip_bfloat16* W3t = (__hip_bfloat16*)(ws + w3t_off);
    __hip_bfloat16* h = (__hip_bfloat16*)(ws + h_off);
    float* part = (float*)(ws + part_off);

    // W (41,2048,256) -> Wt (41,256,2048) bf16
    transpose_cast_k<<<dim3(OO / 32, GG / 32, NN), 256, 0, stream>>>(W, Wt, GG, OO);
    // W3 (10496,512) -> W3t (512,10496) bf16
    transpose_cast_k<<<dim3(EE / 32, NO / 32, 1), 256, 0, stream>>>(W3, W3t, NO, EE);
    // gather
    gather_cast_k<<<dim3(128), 256, 0, stream>>>(x, idx, g);
    // GEMM1
    gemm1_k<<<dim3(164), 256, 0, stream>>>(g, Wt, bias, h);
    // GEMM2 split-K partials
    gemm2_k<<<dim3(328), 256, 0, stream>>>(h, W3t, part);
    // reduce + bias + leaky relu
    reduce_k<<<dim3(128), 256, 0, stream>>>(part, b3, out);
}

// Round 3
// 313.196 us; speedup vs baseline: 1.7034x; 1.7034x over previous
//
#include <hip/hip_runtime.h>
#include <hip/hip_bf16.h>

#define NB 256
#define DD 65536
#define NN 41
#define GG 2048
#define OO 256
#define NO 10496
#define EE 512
#define NEG_SLOPE 0.2f

typedef __attribute__((ext_vector_type(8))) short bf16x8;
typedef __attribute__((ext_vector_type(4))) float f32x4;
typedef unsigned int u32;

// ---- transpose + fp32->bf16 cast: src[z][K][Oc] -> dst[z][Oc][K] ----
__global__ __launch_bounds__(256) void transpose_cast_k(const float* __restrict__ src,
                                                        __hip_bfloat16* __restrict__ dst,
                                                        int K, int Oc) {
    __shared__ float tile[32][33];
    size_t slab = (size_t)blockIdx.z * K * Oc;
    int k0 = blockIdx.y * 32, o0 = blockIdx.x * 32;
    int tx = threadIdx.x & 31, ty = threadIdx.x >> 5;  // ty 0..7
    const float* s = src + slab;
#pragma unroll
    for (int i = 0; i < 4; ++i)
        tile[ty + 8 * i][tx] = s[(size_t)(k0 + ty + 8 * i) * Oc + o0 + tx];
    __syncthreads();
    __hip_bfloat16* d = dst + slab;
    int o = threadIdx.x >> 4;   // 0..15
    int kp = threadIdx.x & 15;  // k pair
#pragma unroll
    for (int i2 = 0; i2 < 2; ++i2) {
        int oo = o + 16 * i2;
        __hip_bfloat162 p;
        p.x = __float2bfloat16(tile[2 * kp][oo]);
        p.y = __float2bfloat16(tile[2 * kp + 1][oo]);
        *(__hip_bfloat162*)&d[(size_t)(o0 + oo) * K + k0 + 2 * kp] = p;
    }
}

// ---- gather via LDS-staged half row ----
// grid 512 = 256 rows x 2 halves; block 512 thr. Each block casts its half of
// x[b] (32768 floats -> 64 KiB bf16 LDS), then scans ALL idx and serves the
// indices falling in its half. 2 blocks/CU, 8 waves each.
__global__ __launch_bounds__(512) void gather_half_k(const float* __restrict__ x,
                                                     const int* __restrict__ idx,
                                                     __hip_bfloat16* __restrict__ g) {
    __shared__ __align__(16) __hip_bfloat16 xr[32768];  // 64 KiB
    int b = blockIdx.x >> 1;
    int h = blockIdx.x & 1;
    int t = threadIdx.x;
    const float4* xv = (const float4*)(x + (size_t)b * DD + h * 32768);
#pragma unroll
    for (int i = 0; i < 16; ++i) {
        float4 v = xv[t + 512 * i];
        short4 p;
        p.x = (short)__bfloat16_as_ushort(__float2bfloat16(v.x));
        p.y = (short)__bfloat16_as_ushort(__float2bfloat16(v.y));
        p.z = (short)__bfloat16_as_ushort(__float2bfloat16(v.z));
        p.w = (short)__bfloat16_as_ushort(__float2bfloat16(v.w));
        *(short4*)&xr[(t + 512 * i) * 4] = p;
    }
    __syncthreads();
    const int4* idx4 = (const int4*)idx;
    // NN*GG/4 = 20992 = 41 * 512 -> exactly 41 iters/thread
    for (int u = t; u < NN * GG / 4; u += 512) {
        int4 ii = idx4[u];
        int n = u >> 9;               // u*4 / 2048
        int k = (u & 511) * 4;
        __hip_bfloat16* dst = &g[((size_t)n * NB + b) * GG + k];
        if ((ii.x >> 15) == h) dst[0] = xr[ii.x & 32767];
        if ((ii.y >> 15) == h) dst[1] = xr[ii.y & 32767];
        if ((ii.z >> 15) == h) dst[2] = xr[ii.z & 32767];
        if ((ii.w >> 15) == h) dst[3] = xr[ii.w & 32767];
    }
}

// ---- GEMM1 split-K=2: part1[s][b][n*OO+o] = sum_{k in half s} g[n][b][k]*Wt[n][o][k]
// grid 328 = 41 n * 2 m * 2 o * 2 s; block 512 thr = 8 waves; tile 128x128, BK=32
__global__ __launch_bounds__(512) void gemm1_k(const __hip_bfloat16* __restrict__ g,
                                               const __hip_bfloat16* __restrict__ Wt,
                                               float* __restrict__ part1) {
    int bid = blockIdx.x;
    int n = bid >> 3;
    int s = bid & 1;
    int m0 = ((bid >> 1) & 1) * 128;
    int o0 = ((bid >> 2) & 1) * 128;
    const u32* srcA = (const u32*)(g + ((size_t)n * NB + m0) * GG);
    const u32* srcB = (const u32*)(Wt + ((size_t)n * OO + o0) * GG);
    __shared__ __align__(16) __hip_bfloat16 lA[128 * 32];
    __shared__ __align__(16) __hip_bfloat16 lB[128 * 32];
    int t = threadIdx.x;
    int lane = t & 63, w = t >> 6;
    int mw = (w >> 2) * 64;   // 2 m-waves
    int nw = (w & 3) * 32;    // 4 o-waves
    int lrow = lane & 15, quad = lane >> 4;
    f32x4 acc[4][2] = {};

    for (int k0 = s * 1024; k0 < s * 1024 + 1024; k0 += 32) {
        __syncthreads();
        int kw = k0 >> 1;
#pragma unroll
        for (int i = 0; i < 4; ++i) {
            int u = t + 512 * i;
            int r = u >> 4, kk = u & 15;
            ((u32*)lA)[r * 16 + kk] = srcA[(size_t)r * (GG / 2) + kw + kk];
        }
#pragma unroll
        for (int i = 0; i < 4; ++i) {
            int u = t + 512 * i;
            int r = u >> 4, kk = u & 15;
            ((u32*)lB)[r * 16 + kk] = srcB[(size_t)r * (GG / 2) + kw + kk];
        }
        __syncthreads();
        bf16x8 af[4];
#pragma unroll
        for (int fm = 0; fm < 4; ++fm)
            af[fm] = *(const bf16x8*)&lA[(mw + fm * 16 + lrow) * 32 + quad * 8];
#pragma unroll
        for (int fn = 0; fn < 2; ++fn) {
            bf16x8 bfr = *(const bf16x8*)&lB[(nw + fn * 16 + lrow) * 32 + quad * 8];
#pragma unroll
            for (int fm = 0; fm < 4; ++fm)
                acc[fm][fn] = __builtin_amdgcn_mfma_f32_16x16x32_bf16(af[fm], bfr, acc[fm][fn], 0, 0, 0);
        }
    }
    // C/D layout: col=lane&15, row=quad*4+reg
#pragma unroll
    for (int fm = 0; fm < 4; ++fm) {
#pragma unroll
        for (int fn = 0; fn < 2; ++fn) {
            int col = o0 + nw + fn * 16 + lrow;
#pragma unroll
            for (int r = 0; r < 4; ++r) {
                int row = m0 + mw + fm * 16 + quad * 4 + r;
                part1[((size_t)s * NB + row) * NO + n * OO + col] = acc[fm][fn][r];
            }
        }
    }
}

// ---- combine GEMM1 partials + bias -> h bf16 ----
__global__ __launch_bounds__(256) void combine1_k(const float* __restrict__ part1,
                                                  const float* __restrict__ bias,
                                                  __hip_bfloat16* __restrict__ h) {
    int j4 = blockIdx.x * 256 + threadIdx.x;  // float4 index over 256*10496/4
    const float4* p0 = (const float4*)part1;
    const float4* p1 = p0 + (size_t)NB * NO / 4;
    int jj = j4 % (NO / 4);  // position within row
    float4 a = p0[j4], c = p1[j4];
    float4 bv = ((const float4*)bias)[jj];
    a.x += c.x + bv.x; a.y += c.y + bv.y; a.z += c.z + bv.z; a.w += c.w + bv.w;
    ushort4 o;
    o.x = __bfloat16_as_ushort(__float2bfloat16(a.x));
    o.y = __bfloat16_as_ushort(__float2bfloat16(a.y));
    o.z = __bfloat16_as_ushort(__float2bfloat16(a.z));
    o.w = __bfloat16_as_ushort(__float2bfloat16(a.w));
    *(ushort4*)&h[(size_t)j4 * 4] = o;
}

// ---- GEMM2 split-K: part[s][b][e] = sum_{k in chunk s} h[b][k]*W3t[e][k]
// grid 656 = 41 s * 2 m * 8 e; block 256 thr; tile 128x64, Kchunk=256, BK=32
__global__ __launch_bounds__(256) void gemm2_k(const __hip_bfloat16* __restrict__ h,
                                               const __hip_bfloat16* __restrict__ W3t,
                                               float* __restrict__ part) {
    int bid = blockIdx.x;
    int s = bid >> 4;            // 0..40
    int m0 = ((bid >> 3) & 1) * 128;
    int e0 = (bid & 7) * 64;
    const u32* srcA = (const u32*)h + (size_t)m0 * (NO / 2);
    const u32* srcB = (const u32*)(W3t + (size_t)e0 * NO);
    __shared__ __align__(16) __hip_bfloat16 lA[128 * 32];
    __shared__ __align__(16) __hip_bfloat16 lB[64 * 32];
    int t = threadIdx.x;
    int lane = t & 63, w = t >> 6;
    int mw = (w >> 1) * 64, nw = (w & 1) * 32;
    int lrow = lane & 15, quad = lane >> 4;
    f32x4 acc[4][2] = {};

    for (int k0 = s * 256; k0 < s * 256 + 256; k0 += 32) {
        __syncthreads();
        int kw = k0 >> 1;
#pragma unroll
        for (int i = 0; i < 8; ++i) {
            int u = t + 256 * i;
            int r = u >> 4, kk = u & 15;
            ((u32*)lA)[r * 16 + kk] = srcA[(size_t)r * (NO / 2) + kw + kk];
        }
#pragma unroll
        for (int i = 0; i < 4; ++i) {
            int u = t + 256 * i;
            int r = u >> 4, kk = u & 15;
            ((u32*)lB)[r * 16 + kk] = srcB[(size_t)r * (NO / 2) + kw + kk];
        }
        __syncthreads();
        bf16x8 af[4];
#pragma unroll
        for (int fm = 0; fm < 4; ++fm)
            af[fm] = *(const bf16x8*)&lA[(mw + fm * 16 + lrow) * 32 + quad * 8];
#pragma unroll
        for (int fn = 0; fn < 2; ++fn) {
            bf16x8 bfr = *(const bf16x8*)&lB[(nw + fn * 16 + lrow) * 32 + quad * 8];
#pragma unroll
            for (int fm = 0; fm < 4; ++fm)
                acc[fm][fn] = __builtin_amdgcn_mfma_f32_16x16x32_bf16(af[fm], bfr, acc[fm][fn], 0, 0, 0);
        }
    }
#pragma unroll
    for (int fm = 0; fm < 4; ++fm) {
#pragma unroll
        for (int fn = 0; fn < 2; ++fn) {
            int e = e0 + nw + fn * 16 + lrow;
#pragma unroll
            for (int r = 0; r < 4; ++r) {
                int row = m0 + mw + fm * 16 + quad * 4 + r;
                part[((size_t)s * NB + row) * EE + e] = acc[fm][fn][r];
            }
        }
    }
}

// ---- reduce partials + bias + leaky relu ----
__global__ __launch_bounds__(256) void reduce_k(const float* __restrict__ part,
                                                const float* __restrict__ b3,
                                                float* __restrict__ out) {
    int j = blockIdx.x * 256 + threadIdx.x;  // float4 index over 256*512
    float4 a = make_float4(0.f, 0.f, 0.f, 0.f);
    for (int s = 0; s < NN; ++s) {
        float4 v = ((const float4*)part)[(size_t)s * (NB * EE / 4) + j];
        a.x += v.x; a.y += v.y; a.z += v.z; a.w += v.w;
    }
    float4 bv = ((const float4*)b3)[j & 127];
    a.x += bv.x; a.y += bv.y; a.z += bv.z; a.w += bv.w;
    a.x = a.x >= 0.f ? a.x : NEG_SLOPE * a.x;
    a.y = a.y >= 0.f ? a.y : NEG_SLOPE * a.y;
    a.z = a.z >= 0.f ? a.z : NEG_SLOPE * a.z;
    a.w = a.w >= 0.f ? a.w : NEG_SLOPE * a.w;
    ((float4*)out)[j] = a;
}

extern "C" void kernel_launch(void* const* d_in, const int* in_sizes, int n_in,
                              void* d_out, int out_size, void* d_ws, size_t ws_size,
                              hipStream_t stream) {
    const float* x = (const float*)d_in[0];
    const int* idx = (const int*)d_in[1];
    const float* W = (const float*)d_in[2];
    const float* bias = (const float*)d_in[3];
    const float* W3 = (const float*)d_in[4];
    const float* b3 = (const float*)d_in[5];
    float* out = (float*)d_out;

    char* ws = (char*)d_ws;
    const size_t g_off = 0;
    const size_t g_sz = (size_t)NN * NB * GG * 2;          // 42,991,616
    const size_t wt_off = g_off + g_sz;
    const size_t wt_sz = (size_t)NN * GG * OO * 2;         // 42,991,616
    const size_t w3t_off = wt_off + wt_sz;
    const size_t w3t_sz = (size_t)NO * EE * 2;             // 10,747,904
    const size_t h_off = w3t_off + w3t_sz;
    const size_t h_sz = (size_t)NB * NO * 2;               // 5,373,952
    const size_t p_off = h_off + h_sz;
    // part1 (2*NB*NO*4 = 21.5 MB) aliases part (41*NB*EE*4 = 21.5 MB):
    // part1 is dead after combine1_k, before gemm2_k writes part.

    __hip_bfloat16* g = (__hip_bfloat16*)(ws + g_off);
    __hip_bfloat16* Wt = (__hip_bfloat16*)(ws + wt_off);
    __hip_bfloat16* W3t = (__hip_bfloat16*)(ws + w3t_off);
    __hip_bfloat16* h = (__hip_bfloat16*)(ws + h_off);
    float* part1 = (float*)(ws + p_off);
    float* part = (float*)(ws + p_off);

    // W (41,2048,256) -> Wt (41,256,2048) bf16
    transpose_cast_k<<<dim3(OO / 32, GG / 32, NN), 256, 0, stream>>>(W, Wt, GG, OO);
    // W3 (10496,512) -> W3t (512,10496) bf16
    transpose_cast_k<<<dim3(EE / 32, NO / 32, 1), 256, 0, stream>>>(W3, W3t, NO, EE);
    // gather via LDS-staged half rows
    gather_half_k<<<dim3(512), 512, 0, stream>>>(x, idx, g);
    // GEMM1 split-K=2 -> fp32 partials
    gemm1_k<<<dim3(328), 512, 0, stream>>>(g, Wt, part1);
    // combine partials + bias -> h bf16
    combine1_k<<<dim3(NB * NO / 4 / 256), 256, 0, stream>>>(part1, bias, h);
    // GEMM2 split-K partials
    gemm2_k<<<dim3(656), 256, 0, stream>>>(h, W3t, part);
    // reduce + bias + leaky relu
    reduce_k<<<dim3(128), 256, 0, stream>>>(part, b3, out);
}

// Round 4
// 308.498 us; speedup vs baseline: 1.7293x; 1.0152x over previous
//
#include <hip/hip_runtime.h>
#include <hip/hip_bf16.h>

#define NB 256
#define DD 65536
#define NN 41
#define GG 2048
#define OO 256
#define NO 10496
#define EE 512
#define NEG_SLOPE 0.2f

typedef __attribute__((ext_vector_type(8))) short bf16x8;
typedef __attribute__((ext_vector_type(4))) float f32x4;
typedef unsigned int u32;

// async global->LDS, 16B per lane. LDS dest must be uniform-base + lane*16.
__device__ __forceinline__ void gl_lds16(const __hip_bfloat16* gsrc, __hip_bfloat16* lds) {
    __builtin_amdgcn_global_load_lds((const __attribute__((address_space(1))) u32*)gsrc,
                                     (__attribute__((address_space(3))) u32*)lds, 16, 0, 0);
}

// ---- transpose + fp32->bf16 cast: src[z][K][Oc] -> dst[z][Oc][K] ----
__global__ __launch_bounds__(256) void transpose_cast_k(const float* __restrict__ src,
                                                        __hip_bfloat16* __restrict__ dst,
                                                        int K, int Oc) {
    __shared__ float tile[32][33];
    size_t slab = (size_t)blockIdx.z * K * Oc;
    int k0 = blockIdx.y * 32, o0 = blockIdx.x * 32;
    int tx = threadIdx.x & 31, ty = threadIdx.x >> 5;  // ty 0..7
    const float* s = src + slab;
#pragma unroll
    for (int i = 0; i < 4; ++i)
        tile[ty + 8 * i][tx] = s[(size_t)(k0 + ty + 8 * i) * Oc + o0 + tx];
    __syncthreads();
    __hip_bfloat16* d = dst + slab;
    int o = threadIdx.x >> 4;   // 0..15
    int kp = threadIdx.x & 15;  // k pair
#pragma unroll
    for (int i2 = 0; i2 < 2; ++i2) {
        int oo = o + 16 * i2;
        __hip_bfloat162 p;
        p.x = __float2bfloat16(tile[2 * kp][oo]);
        p.y = __float2bfloat16(tile[2 * kp + 1][oo]);
        *(__hip_bfloat162*)&d[(size_t)(o0 + oo) * K + k0 + 2 * kp] = p;
    }
}

// ---- gather, full row in 128 KiB dynamic LDS: one block per row b ----
// Every index hits -> unconditional coalesced 8B stores, single scan.
__global__ __launch_bounds__(512) void gather_full_k(const float* __restrict__ x,
                                                     const int* __restrict__ idx,
                                                     __hip_bfloat16* __restrict__ g) {
    extern __shared__ __hip_bfloat16 xr[];  // 131072 bytes
    int b = blockIdx.x;
    int t = threadIdx.x;
    const float4* xv = (const float4*)(x + (size_t)b * DD);
#pragma unroll
    for (int i = 0; i < 32; ++i) {
        float4 v = xv[t + 512 * i];
        short4 p;
        p.x = (short)__bfloat16_as_ushort(__float2bfloat16(v.x));
        p.y = (short)__bfloat16_as_ushort(__float2bfloat16(v.y));
        p.z = (short)__bfloat16_as_ushort(__float2bfloat16(v.z));
        p.w = (short)__bfloat16_as_ushort(__float2bfloat16(v.w));
        *(short4*)&xr[(t + 512 * i) * 4] = p;
    }
    __syncthreads();
    const int4* idx4 = (const int4*)idx;
#pragma unroll 1
    for (int it = 0; it < 41; ++it) {
        int u = t + 512 * it;          // 512 int4-groups per n (GG/4=512)
        int n = u >> 9;
        int k = (u & 511) * 4;
        int4 ii = idx4[u];
        ushort4 o;
        o.x = __bfloat16_as_ushort(xr[ii.x]);
        o.y = __bfloat16_as_ushort(xr[ii.y]);
        o.z = __bfloat16_as_ushort(xr[ii.z]);
        o.w = __bfloat16_as_ushort(xr[ii.w]);
        *(ushort4*)&g[((size_t)n * NB + b) * GG + k] = o;
    }
}

// ---- fallback gather (half row in 64 KiB static LDS), if >64KiB LDS unavailable ----
__global__ __launch_bounds__(512) void gather_half_k(const float* __restrict__ x,
                                                     const int* __restrict__ idx,
                                                     __hip_bfloat16* __restrict__ g) {
    __shared__ __align__(16) __hip_bfloat16 xr[32768];
    int b = blockIdx.x >> 1;
    int h = blockIdx.x & 1;
    int t = threadIdx.x;
    const float4* xv = (const float4*)(x + (size_t)b * DD + h * 32768);
#pragma unroll
    for (int i = 0; i < 16; ++i) {
        float4 v = xv[t + 512 * i];
        short4 p;
        p.x = (short)__bfloat16_as_ushort(__float2bfloat16(v.x));
        p.y = (short)__bfloat16_as_ushort(__float2bfloat16(v.y));
        p.z = (short)__bfloat16_as_ushort(__float2bfloat16(v.z));
        p.w = (short)__bfloat16_as_ushort(__float2bfloat16(v.w));
        *(short4*)&xr[(t + 512 * i) * 4] = p;
    }
    __syncthreads();
    const int4* idx4 = (const int4*)idx;
    for (int u = t; u < NN * GG / 4; u += 512) {
        int4 ii = idx4[u];
        int n = u >> 9;
        int k = (u & 511) * 4;
        __hip_bfloat16* dst = &g[((size_t)n * NB + b) * GG + k];
        if ((ii.x >> 15) == h) dst[0] = xr[ii.x & 32767];
        if ((ii.y >> 15) == h) dst[1] = xr[ii.y & 32767];
        if ((ii.z >> 15) == h) dst[2] = xr[ii.z & 32767];
        if ((ii.w >> 15) == h) dst[3] = xr[ii.w & 32767];
    }
}

// ---- GEMM1: h[b][n*OO+o] = bf16(sum_k g[n][b][k]*Wt[n][o][k] + bias[n][o])
// grid 164 = 41 n * 2 m * 2 o; 256 thr = 4 waves; tile 128x128, wave 64x64, BK=32
__global__ __launch_bounds__(256) void gemm1_k(const __hip_bfloat16* __restrict__ g,
                                               const __hip_bfloat16* __restrict__ Wt,
                                               const float* __restrict__ bias,
                                               __hip_bfloat16* __restrict__ h) {
    int bid = blockIdx.x;
    int n = bid >> 2;
    int m0 = ((bid >> 1) & 1) * 128;
    int o0 = (bid & 1) * 128;
    const __hip_bfloat16* srcA = g + ((size_t)n * NB + m0) * GG;
    const __hip_bfloat16* srcB = Wt + ((size_t)n * OO + o0) * GG;
    __shared__ __align__(16) __hip_bfloat16 lA[128 * 32];
    __shared__ __align__(16) __hip_bfloat16 lB[128 * 32];
    int t = threadIdx.x;
    int lane = t & 63, w = t >> 6;
    int mw = (w >> 1) * 64, nw = (w & 1) * 64;
    int lrow = lane & 15, quad = lane >> 4;
    // chunk mapping: c = t + 256*i; row r=c>>2, quarter q=c&3; LDS elem = c*8
    int r0 = t >> 2, q0 = (t & 3) * 8;
    f32x4 acc[4][4] = {};

    for (int k0 = 0; k0 < GG; k0 += 32) {
        __syncthreads();
        gl_lds16(srcA + (size_t)r0 * GG + k0 + q0, lA + t * 8);
        gl_lds16(srcA + (size_t)(r0 + 64) * GG + k0 + q0, lA + (t + 256) * 8);
        gl_lds16(srcB + (size_t)r0 * GG + k0 + q0, lB + t * 8);
        gl_lds16(srcB + (size_t)(r0 + 64) * GG + k0 + q0, lB + (t + 256) * 8);
        __syncthreads();
        bf16x8 af[4];
#pragma unroll
        for (int fm = 0; fm < 4; ++fm)
            af[fm] = *(const bf16x8*)&lA[(mw + fm * 16 + lrow) * 32 + quad * 8];
#pragma unroll
        for (int fn = 0; fn < 4; ++fn) {
            bf16x8 bfr = *(const bf16x8*)&lB[(nw + fn * 16 + lrow) * 32 + quad * 8];
#pragma unroll
            for (int fm = 0; fm < 4; ++fm)
                acc[fm][fn] = __builtin_amdgcn_mfma_f32_16x16x32_bf16(af[fm], bfr, acc[fm][fn], 0, 0, 0);
        }
    }
    // C/D layout: col=lane&15, row=quad*4+reg
#pragma unroll
    for (int fm = 0; fm < 4; ++fm) {
#pragma unroll
        for (int fn = 0; fn < 4; ++fn) {
            int col = o0 + nw + fn * 16 + lrow;
            float bv = bias[n * OO + col];
#pragma unroll
            for (int r = 0; r < 4; ++r) {
                int row = m0 + mw + fm * 16 + quad * 4 + r;
                h[(size_t)row * NO + n * OO + col] = __float2bfloat16(acc[fm][fn][r] + bv);
            }
        }
    }
}

// ---- GEMM2 split-K: part[s][b][e] = sum_{k in chunk s} h[b][k]*W3t[e][k]
// grid 328 = 41 s * 2 m * 4 e; 256 thr; tile 128x128, wave 64x64, Kchunk=256
__global__ __launch_bounds__(256) void gemm2_k(const __hip_bfloat16* __restrict__ h,
                                               const __hip_bfloat16* __restrict__ W3t,
                                               float* __restrict__ part) {
    int bid = blockIdx.x;
    int s = bid >> 3;
    int m0 = ((bid >> 2) & 1) * 128;
    int e0 = (bid & 3) * 128;
    const __hip_bfloat16* srcA = h + (size_t)m0 * NO;
    const __hip_bfloat16* srcB = W3t + (size_t)e0 * NO;
    __shared__ __align__(16) __hip_bfloat16 lA[128 * 32];
    __shared__ __align__(16) __hip_bfloat16 lB[128 * 32];
    int t = threadIdx.x;
    int lane = t & 63, w = t >> 6;
    int mw = (w >> 1) * 64, nw = (w & 1) * 64;
    int lrow = lane & 15, quad = lane >> 4;
    int r0 = t >> 2, q0 = (t & 3) * 8;
    f32x4 acc[4][4] = {};

    for (int k0 = s * 256; k0 < s * 256 + 256; k0 += 32) {
        __syncthreads();
        gl_lds16(srcA + (size_t)r0 * NO + k0 + q0, lA + t * 8);
        gl_lds16(srcA + (size_t)(r0 + 64) * NO + k0 + q0, lA + (t + 256) * 8);
        gl_lds16(srcB + (size_t)r0 * NO + k0 + q0, lB + t * 8);
        gl_lds16(srcB + (size_t)(r0 + 64) * NO + k0 + q0, lB + (t + 256) * 8);
        __syncthreads();
        bf16x8 af[4];
#pragma unroll
        for (int fm = 0; fm < 4; ++fm)
            af[fm] = *(const bf16x8*)&lA[(mw + fm * 16 + lrow) * 32 + quad * 8];
#pragma unroll
        for (int fn = 0; fn < 4; ++fn) {
            bf16x8 bfr = *(const bf16x8*)&lB[(nw + fn * 16 + lrow) * 32 + quad * 8];
#pragma unroll
            for (int fm = 0; fm < 4; ++fm)
                acc[fm][fn] = __builtin_amdgcn_mfma_f32_16x16x32_bf16(af[fm], bfr, acc[fm][fn], 0, 0, 0);
        }
    }
#pragma unroll
    for (int fm = 0; fm < 4; ++fm) {
#pragma unroll
        for (int fn = 0; fn < 4; ++fn) {
            int e = e0 + nw + fn * 16 + lrow;
#pragma unroll
            for (int r = 0; r < 4; ++r) {
                int row = m0 + mw + fm * 16 + quad * 4 + r;
                part[((size_t)s * NB + row) * EE + e] = acc[fm][fn][r];
            }
        }
    }
}

// ---- reduce partials + bias + leaky relu ----
__global__ __launch_bounds__(256) void reduce_k(const float* __restrict__ part,
                                                const float* __restrict__ b3,
                                                float* __restrict__ out) {
    int j = blockIdx.x * 256 + threadIdx.x;  // float4 index over 256*512
    float4 a = make_float4(0.f, 0.f, 0.f, 0.f);
    for (int s = 0; s < NN; ++s) {
        float4 v = ((const float4*)part)[(size_t)s * (NB * EE / 4) + j];
        a.x += v.x; a.y += v.y; a.z += v.z; a.w += v.w;
    }
    float4 bv = ((const float4*)b3)[j & 127];
    a.x += bv.x; a.y += bv.y; a.z += bv.z; a.w += bv.w;
    a.x = a.x >= 0.f ? a.x : NEG_SLOPE * a.x;
    a.y = a.y >= 0.f ? a.y : NEG_SLOPE * a.y;
    a.z = a.z >= 0.f ? a.z : NEG_SLOPE * a.z;
    a.w = a.w >= 0.f ? a.w : NEG_SLOPE * a.w;
    ((float4*)out)[j] = a;
}

extern "C" void kernel_launch(void* const* d_in, const int* in_sizes, int n_in,
                              void* d_out, int out_size, void* d_ws, size_t ws_size,
                              hipStream_t stream) {
    const float* x = (const float*)d_in[0];
    const int* idx = (const int*)d_in[1];
    const float* W = (const float*)d_in[2];
    const float* bias = (const float*)d_in[3];
    const float* W3 = (const float*)d_in[4];
    const float* b3 = (const float*)d_in[5];
    float* out = (float*)d_out;

    char* ws = (char*)d_ws;
    const size_t g_off = 0;
    const size_t g_sz = (size_t)NN * NB * GG * 2;
    const size_t wt_off = g_off + g_sz;
    const size_t wt_sz = (size_t)NN * GG * OO * 2;
    const size_t w3t_off = wt_off + wt_sz;
    const size_t w3t_sz = (size_t)NO * EE * 2;
    const size_t h_off = w3t_off + w3t_sz;
    const size_t h_sz = (size_t)NB * NO * 2;
    const size_t p_off = h_off + h_sz;

    __hip_bfloat16* g = (__hip_bfloat16*)(ws + g_off);
    __hip_bfloat16* Wt = (__hip_bfloat16*)(ws + wt_off);
    __hip_bfloat16* W3t = (__hip_bfloat16*)(ws + w3t_off);
    __hip_bfloat16* h = (__hip_bfloat16*)(ws + h_off);
    float* part = (float*)(ws + p_off);

    // W (41,2048,256) -> Wt (41,256,2048) bf16
    transpose_cast_k<<<dim3(OO / 32, GG / 32, NN), 256, 0, stream>>>(W, Wt, GG, OO);
    // W3 (10496,512) -> W3t (512,10496) bf16
    transpose_cast_k<<<dim3(EE / 32, NO / 32, 1), 256, 0, stream>>>(W3, W3t, NO, EE);
    // gather: full 128 KiB row in dynamic LDS if allowed, else half-row fallback
    hipError_t aerr = hipFuncSetAttribute(reinterpret_cast<const void*>(gather_full_k),
                                          hipFuncAttributeMaxDynamicSharedMemorySize, 131072);
    if (aerr == hipSuccess) {
        gather_full_k<<<dim3(NB), 512, 131072, stream>>>(x, idx, g);
    } else {
        gather_half_k<<<dim3(512), 512, 0, stream>>>(x, idx, g);
    }
    // GEMM1 (bias + bf16 cast fused)
    gemm1_k<<<dim3(164), 256, 0, stream>>>(g, Wt, bias, h);
    // GEMM2 split-K partials
    gemm2_k<<<dim3(328), 256, 0, stream>>>(h, W3t, part);
    // reduce + bias + leaky relu
    reduce_k<<<dim3(128), 256, 0, stream>>>(part, b3, out);
}

// Round 5
// 276.711 us; speedup vs baseline: 1.9279x; 1.1149x over previous
//
#include <hip/hip_runtime.h>
#include <hip/hip_bf16.h>

#define NB 256
#define DD 65536
#define NN 41
#define GG 2048
#define OO 256
#define NO 10496
#define EE 512
#define NEG_SLOPE 0.2f

typedef __attribute__((ext_vector_type(8))) short bf16x8;
typedef __attribute__((ext_vector_type(4))) float f32x4;
typedef unsigned int u32;

// async global->LDS, 16B per lane. LDS dest must be wave-uniform base + lane*16.
__device__ __forceinline__ void gl_lds16(const __hip_bfloat16* gsrc, __hip_bfloat16* lds) {
    __builtin_amdgcn_global_load_lds((const __attribute__((address_space(1))) u32*)gsrc,
                                     (__attribute__((address_space(3))) u32*)lds, 16, 0, 0);
}

// ---- transpose + fp32->bf16 cast: src[z][K][Oc] -> dst[z][Oc][K] ----
__global__ __launch_bounds__(256) void transpose_cast_k(const float* __restrict__ src,
                                                        __hip_bfloat16* __restrict__ dst,
                                                        int K, int Oc) {
    __shared__ float tile[32][33];
    size_t slab = (size_t)blockIdx.z * K * Oc;
    int k0 = blockIdx.y * 32, o0 = blockIdx.x * 32;
    int tx = threadIdx.x & 31, ty = threadIdx.x >> 5;  // ty 0..7
    const float* s = src + slab;
#pragma unroll
    for (int i = 0; i < 4; ++i)
        tile[ty + 8 * i][tx] = s[(size_t)(k0 + ty + 8 * i) * Oc + o0 + tx];
    __syncthreads();
    __hip_bfloat16* d = dst + slab;
    int o = threadIdx.x >> 4;   // 0..15
    int kp = threadIdx.x & 15;  // k pair
#pragma unroll
    for (int i2 = 0; i2 < 2; ++i2) {
        int oo = o + 16 * i2;
        __hip_bfloat162 p;
        p.x = __float2bfloat16(tile[2 * kp][oo]);
        p.y = __float2bfloat16(tile[2 * kp + 1][oo]);
        *(__hip_bfloat162*)&d[(size_t)(o0 + oo) * K + k0 + 2 * kp] = p;
    }
}

// ---- gather, full row in 128 KiB dynamic LDS: one block per row b ----
__global__ __launch_bounds__(512) void gather_full_k(const float* __restrict__ x,
                                                     const int* __restrict__ idx,
                                                     __hip_bfloat16* __restrict__ g) {
    extern __shared__ __hip_bfloat16 xr[];  // 131072 bytes
    int b = blockIdx.x;
    int t = threadIdx.x;
    const float4* xv = (const float4*)(x + (size_t)b * DD);
#pragma unroll
    for (int i = 0; i < 32; ++i) {
        float4 v = xv[t + 512 * i];
        short4 p;
        p.x = (short)__bfloat16_as_ushort(__float2bfloat16(v.x));
        p.y = (short)__bfloat16_as_ushort(__float2bfloat16(v.y));
        p.z = (short)__bfloat16_as_ushort(__float2bfloat16(v.z));
        p.w = (short)__bfloat16_as_ushort(__float2bfloat16(v.w));
        *(short4*)&xr[(t + 512 * i) * 4] = p;
    }
    __syncthreads();
    const int4* idx4 = (const int4*)idx;
#pragma unroll 1
    for (int n = 0; n < NN; ++n) {
        int4 ii = idx4[n * 512 + t];
        ushort4 o;
        o.x = __bfloat16_as_ushort(xr[ii.x]);
        o.y = __bfloat16_as_ushort(xr[ii.y]);
        o.z = __bfloat16_as_ushort(xr[ii.z]);
        o.w = __bfloat16_as_ushort(xr[ii.w]);
        *(ushort4*)&g[((size_t)n * NB + b) * GG + t * 4] = o;
    }
}

// ---- fallback gather (half row in 64 KiB static LDS) ----
__global__ __launch_bounds__(512) void gather_half_k(const float* __restrict__ x,
                                                     const int* __restrict__ idx,
                                                     __hip_bfloat16* __restrict__ g) {
    __shared__ __align__(16) __hip_bfloat16 xr[32768];
    int b = blockIdx.x >> 1;
    int h = blockIdx.x & 1;
    int t = threadIdx.x;
    const float4* xv = (const float4*)(x + (size_t)b * DD + h * 32768);
#pragma unroll
    for (int i = 0; i < 16; ++i) {
        float4 v = xv[t + 512 * i];
        short4 p;
        p.x = (short)__bfloat16_as_ushort(__float2bfloat16(v.x));
        p.y = (short)__bfloat16_as_ushort(__float2bfloat16(v.y));
        p.z = (short)__bfloat16_as_ushort(__float2bfloat16(v.z));
        p.w = (short)__bfloat16_as_ushort(__float2bfloat16(v.w));
        *(short4*)&xr[(t + 512 * i) * 4] = p;
    }
    __syncthreads();
    const int4* idx4 = (const int4*)idx;
    for (int u = t; u < NN * GG / 4; u += 512) {
        int4 ii = idx4[u];
        int n = u >> 9;
        int k = (u & 511) * 4;
        __hip_bfloat16* dst = &g[((size_t)n * NB + b) * GG + k];
        if ((ii.x >> 15) == h) dst[0] = xr[ii.x & 32767];
        if ((ii.y >> 15) == h) dst[1] = xr[ii.y & 32767];
        if ((ii.z >> 15) == h) dst[2] = xr[ii.z & 32767];
        if ((ii.w >> 15) == h) dst[3] = xr[ii.w & 32767];
    }
}

// ---- GEMM1 split-K=2, double-buffered global_load_lds.
// grid 328 = 41 n * 2 m * 2 o * 2 s; 512 thr = 8 waves (64x32 wave tile);
// tile 128x128, BK=32, 32 K-iters/block.
__global__ __launch_bounds__(512) void gemm1_k(const __hip_bfloat16* __restrict__ g,
                                               const __hip_bfloat16* __restrict__ Wt,
                                               float* __restrict__ part1) {
    int bid = blockIdx.x;
    int n = bid >> 3;
    int s = bid & 1;
    int m0 = ((bid >> 1) & 1) * 128;
    int o0 = ((bid >> 2) & 1) * 128;
    const __hip_bfloat16* srcA = g + ((size_t)n * NB + m0) * GG + s * 1024;
    const __hip_bfloat16* srcB = Wt + ((size_t)n * OO + o0) * GG + s * 1024;
    __shared__ __align__(16) __hip_bfloat16 lA[2][128 * 32];
    __shared__ __align__(16) __hip_bfloat16 lB[2][128 * 32];
    int t = threadIdx.x;
    int lane = t & 63, w = t >> 6;
    int mw = (w >> 2) * 64;   // 2 m-waves
    int ow = (w & 3) * 32;    // 4 o-waves
    int lrow = lane & 15, quad = lane >> 4;
    int r0 = t >> 2, q0 = (t & 3) * 8;  // staging: row, k-offset (128x32 tile, 16B/lane)
    size_t offA = (size_t)r0 * GG + q0;
    size_t offB = (size_t)r0 * GG + q0;
    f32x4 acc[4][2] = {};

    // prologue: stage iter 0 into buf 0
    gl_lds16(srcA + offA, &lA[0][t * 8]);
    gl_lds16(srcB + offB, &lB[0][t * 8]);
    __syncthreads();
#pragma unroll 1
    for (int it = 0; it < 32; ++it) {
        int cur = it & 1;
        if (it + 1 < 32) {
            int k1 = (it + 1) * 32;
            gl_lds16(srcA + offA + k1, &lA[1 - cur][t * 8]);
            gl_lds16(srcB + offB + k1, &lB[1 - cur][t * 8]);
        }
        bf16x8 af[4];
#pragma unroll
        for (int fm = 0; fm < 4; ++fm)
            af[fm] = *(const bf16x8*)&lA[cur][(mw + fm * 16 + lrow) * 32 + quad * 8];
#pragma unroll
        for (int fn = 0; fn < 2; ++fn) {
            bf16x8 bfr = *(const bf16x8*)&lB[cur][(ow + fn * 16 + lrow) * 32 + quad * 8];
#pragma unroll
            for (int fm = 0; fm < 4; ++fm)
                acc[fm][fn] = __builtin_amdgcn_mfma_f32_16x16x32_bf16(af[fm], bfr, acc[fm][fn], 0, 0, 0);
        }
        __syncthreads();  // drains lgkm (cur reads) + vmcnt (next-buf stage)
    }
    // C/D layout: col=lane&15, row=quad*4+reg
#pragma unroll
    for (int fm = 0; fm < 4; ++fm) {
#pragma unroll
        for (int fn = 0; fn < 2; ++fn) {
            int col = o0 + ow + fn * 16 + lrow;
#pragma unroll
            for (int r = 0; r < 4; ++r) {
                int row = m0 + mw + fm * 16 + quad * 4 + r;
                part1[((size_t)s * NB + row) * NO + n * OO + col] = acc[fm][fn][r];
            }
        }
    }
}

// ---- combine GEMM1 partials + bias -> h bf16 ----
__global__ __launch_bounds__(256) void combine1_k(const float* __restrict__ part1,
                                                  const float* __restrict__ bias,
                                                  __hip_bfloat16* __restrict__ h) {
    int j4 = blockIdx.x * 256 + threadIdx.x;  // float4 index over 256*10496/4
    const float4* p0 = (const float4*)part1;
    const float4* p1 = p0 + (size_t)NB * NO / 4;
    int jj = j4 % (NO / 4);
    float4 a = p0[j4], c = p1[j4];
    float4 bv = ((const float4*)bias)[jj];
    a.x += c.x + bv.x; a.y += c.y + bv.y; a.z += c.z + bv.z; a.w += c.w + bv.w;
    ushort4 o;
    o.x = __bfloat16_as_ushort(__float2bfloat16(a.x));
    o.y = __bfloat16_as_ushort(__float2bfloat16(a.y));
    o.z = __bfloat16_as_ushort(__float2bfloat16(a.z));
    o.w = __bfloat16_as_ushort(__float2bfloat16(a.w));
    *(ushort4*)&h[(size_t)j4 * 4] = o;
}

// ---- GEMM2 split-K=41, double-buffered. grid 328 = 41 s * 2 m * 4 e;
// 512 thr = 8 waves (64x32 wave tile); tile 128x128, Kchunk 256, 8 iters.
__global__ __launch_bounds__(512) void gemm2_k(const __hip_bfloat16* __restrict__ h,
                                               const __hip_bfloat16* __restrict__ W3t,
                                               float* __restrict__ part) {
    int bid = blockIdx.x;
    int s = bid >> 3;                 // 0..40
    int m0 = ((bid >> 2) & 1) * 128;
    int e0 = (bid & 3) * 128;
    const __hip_bfloat16* srcA = h + (size_t)m0 * NO + s * 256;
    const __hip_bfloat16* srcB = W3t + (size_t)e0 * NO + s * 256;
    __shared__ __align__(16) __hip_bfloat16 lA[2][128 * 32];
    __shared__ __align__(16) __hip_bfloat16 lB[2][128 * 32];
    int t = threadIdx.x;
    int lane = t & 63, w = t >> 6;
    int mw = (w >> 2) * 64;
    int ew = (w & 3) * 32;
    int lrow = lane & 15, quad = lane >> 4;
    int r0 = t >> 2, q0 = (t & 3) * 8;
    size_t offA = (size_t)r0 * NO + q0;
    size_t offB = (size_t)r0 * NO + q0;
    f32x4 acc[4][2] = {};

    gl_lds16(srcA + offA, &lA[0][t * 8]);
    gl_lds16(srcB + offB, &lB[0][t * 8]);
    __syncthreads();
#pragma unroll 1
    for (int it = 0; it < 8; ++it) {
        int cur = it & 1;
        if (it + 1 < 8) {
            int k1 = (it + 1) * 32;
            gl_lds16(srcA + offA + k1, &lA[1 - cur][t * 8]);
            gl_lds16(srcB + offB + k1, &lB[1 - cur][t * 8]);
        }
        bf16x8 af[4];
#pragma unroll
        for (int fm = 0; fm < 4; ++fm)
            af[fm] = *(const bf16x8*)&lA[cur][(mw + fm * 16 + lrow) * 32 + quad * 8];
#pragma unroll
        for (int fn = 0; fn < 2; ++fn) {
            bf16x8 bfr = *(const bf16x8*)&lB[cur][(ew + fn * 16 + lrow) * 32 + quad * 8];
#pragma unroll
            for (int fm = 0; fm < 4; ++fm)
                acc[fm][fn] = __builtin_amdgcn_mfma_f32_16x16x32_bf16(af[fm], bfr, acc[fm][fn], 0, 0, 0);
        }
        __syncthreads();
    }
#pragma unroll
    for (int fm = 0; fm < 4; ++fm) {
#pragma unroll
        for (int fn = 0; fn < 2; ++fn) {
            int e = e0 + ew + fn * 16 + lrow;
#pragma unroll
            for (int r = 0; r < 4; ++r) {
                int row = m0 + mw + fm * 16 + quad * 4 + r;
                part[((size_t)s * NB + row) * EE + e] = acc[fm][fn][r];
            }
        }
    }
}

// ---- reduce partials + bias + leaky relu ----
__global__ __launch_bounds__(256) void reduce_k(const float* __restrict__ part,
                                                const float* __restrict__ b3,
                                                float* __restrict__ out) {
    int j = blockIdx.x * 256 + threadIdx.x;  // float4 index over 256*512
    float4 a = make_float4(0.f, 0.f, 0.f, 0.f);
    for (int s = 0; s < NN; ++s) {
        float4 v = ((const float4*)part)[(size_t)s * (NB * EE / 4) + j];
        a.x += v.x; a.y += v.y; a.z += v.z; a.w += v.w;
    }
    float4 bv = ((const float4*)b3)[j & 127];
    a.x += bv.x; a.y += bv.y; a.z += bv.z; a.w += bv.w;
    a.x = a.x >= 0.f ? a.x : NEG_SLOPE * a.x;
    a.y = a.y >= 0.f ? a.y : NEG_SLOPE * a.y;
    a.z = a.z >= 0.f ? a.z : NEG_SLOPE * a.z;
    a.w = a.w >= 0.f ? a.w : NEG_SLOPE * a.w;
    ((float4*)out)[j] = a;
}

extern "C" void kernel_launch(void* const* d_in, const int* in_sizes, int n_in,
                              void* d_out, int out_size, void* d_ws, size_t ws_size,
                              hipStream_t stream) {
    const float* x = (const float*)d_in[0];
    const int* idx = (const int*)d_in[1];
    const float* W = (const float*)d_in[2];
    const float* bias = (const float*)d_in[3];
    const float* W3 = (const float*)d_in[4];
    const float* b3 = (const float*)d_in[5];
    float* out = (float*)d_out;

    char* ws = (char*)d_ws;
    const size_t g_off = 0;
    const size_t g_sz = (size_t)NN * NB * GG * 2;
    const size_t wt_off = g_off + g_sz;
    const size_t wt_sz = (size_t)NN * GG * OO * 2;
    const size_t w3t_off = wt_off + wt_sz;
    const size_t w3t_sz = (size_t)NO * EE * 2;
    const size_t h_off = w3t_off + w3t_sz;
    const size_t h_sz = (size_t)NB * NO * 2;
    const size_t p_off = h_off + h_sz;
    // part1 (2*NB*NO*4 = 21.5 MB) aliases part (41*NB*EE*4 = 21.5 MB):
    // part1 dead after combine1_k, before gemm2_k writes part.

    __hip_bfloat16* g = (__hip_bfloat16*)(ws + g_off);
    __hip_bfloat16* Wt = (__hip_bfloat16*)(ws + wt_off);
    __hip_bfloat16* W3t = (__hip_bfloat16*)(ws + w3t_off);
    __hip_bfloat16* h = (__hip_bfloat16*)(ws + h_off);
    float* part1 = (float*)(ws + p_off);
    float* part = (float*)(ws + p_off);

    // W (41,2048,256) -> Wt (41,256,2048) bf16
    transpose_cast_k<<<dim3(OO / 32, GG / 32, NN), 256, 0, stream>>>(W, Wt, GG, OO);
    // W3 (10496,512) -> W3t (512,10496) bf16
    transpose_cast_k<<<dim3(EE / 32, NO / 32, 1), 256, 0, stream>>>(W3, W3t, NO, EE);
    // gather: full 128 KiB row in dynamic LDS if allowed, else half-row fallback
    hipError_t aerr = hipFuncSetAttribute(reinterpret_cast<const void*>(gather_full_k),
                                          hipFuncAttributeMaxDynamicSharedMemorySize, 131072);
    if (aerr == hipSuccess) {
        gather_full_k<<<dim3(NB), 512, 131072, stream>>>(x, idx, g);
    } else {
        gather_half_k<<<dim3(512), 512, 0, stream>>>(x, idx, g);
    }
    // GEMM1 split-K=2, double-buffered
    gemm1_k<<<dim3(328), 512, 0, stream>>>(g, Wt, part1);
    // combine partials + bias -> h bf16
    combine1_k<<<dim3(NB * NO / 4 / 256), 256, 0, stream>>>(part1, bias, h);
    // GEMM2 split-K, double-buffered
    gemm2_k<<<dim3(328), 512, 0, stream>>>(h, W3t, part);
    // reduce + bias + leaky relu
    reduce_k<<<dim3(128), 256, 0, stream>>>(part, b3, out);
}

// Round 6
// 275.267 us; speedup vs baseline: 1.9381x; 1.0052x over previous
//
#include <hip/hip_runtime.h>
#include <hip/hip_bf16.h>

#define NB 256
#define DD 65536
#define NN 41
#define GG 2048
#define OO 256
#define NO 10496
#define EE 512
#define NEG_SLOPE 0.2f

typedef __attribute__((ext_vector_type(8))) short bf16x8;
typedef __attribute__((ext_vector_type(4))) float f32x4;
typedef unsigned int u32;

// async global->LDS, 16B per lane. LDS dest must be wave-uniform base + lane*16.
__device__ __forceinline__ void gl_lds16(const __hip_bfloat16* gsrc, __hip_bfloat16* lds) {
    __builtin_amdgcn_global_load_lds((const __attribute__((address_space(1))) u32*)gsrc,
                                     (__attribute__((address_space(3))) u32*)lds, 16, 0, 0);
}

// ---- transpose + fp32->bf16 cast: src[z][K][Oc] -> dst[z][Oc][K] ----
__global__ __launch_bounds__(256) void transpose_cast_k(const float* __restrict__ src,
                                                        __hip_bfloat16* __restrict__ dst,
                                                        int K, int Oc) {
    __shared__ float tile[32][33];
    size_t slab = (size_t)blockIdx.z * K * Oc;
    int k0 = blockIdx.y * 32, o0 = blockIdx.x * 32;
    int tx = threadIdx.x & 31, ty = threadIdx.x >> 5;  // ty 0..7
    const float* s = src + slab;
#pragma unroll
    for (int i = 0; i < 4; ++i)
        tile[ty + 8 * i][tx] = s[(size_t)(k0 + ty + 8 * i) * Oc + o0 + tx];
    __syncthreads();
    __hip_bfloat16* d = dst + slab;
    int o = threadIdx.x >> 4;   // 0..15
    int kp = threadIdx.x & 15;  // k pair
#pragma unroll
    for (int i2 = 0; i2 < 2; ++i2) {
        int oo = o + 16 * i2;
        __hip_bfloat162 p;
        p.x = __float2bfloat16(tile[2 * kp][oo]);
        p.y = __float2bfloat16(tile[2 * kp + 1][oo]);
        *(__hip_bfloat162*)&d[(size_t)(o0 + oo) * K + k0 + 2 * kp] = p;
    }
}

// ---- gather, full row in 128 KiB dynamic LDS: one block per row b ----
__global__ __launch_bounds__(512) void gather_full_k(const float* __restrict__ x,
                                                     const int* __restrict__ idx,
                                                     __hip_bfloat16* __restrict__ g) {
    extern __shared__ __hip_bfloat16 xr[];  // 131072 bytes
    int b = blockIdx.x;
    int t = threadIdx.x;
    const float4* xv = (const float4*)(x + (size_t)b * DD);
#pragma unroll
    for (int i = 0; i < 32; ++i) {
        float4 v = xv[t + 512 * i];
        short4 p;
        p.x = (short)__bfloat16_as_ushort(__float2bfloat16(v.x));
        p.y = (short)__bfloat16_as_ushort(__float2bfloat16(v.y));
        p.z = (short)__bfloat16_as_ushort(__float2bfloat16(v.z));
        p.w = (short)__bfloat16_as_ushort(__float2bfloat16(v.w));
        *(short4*)&xr[(t + 512 * i) * 4] = p;
    }
    __syncthreads();
    const int4* idx4 = (const int4*)idx;
#pragma unroll 1
    for (int n = 0; n < NN; ++n) {
        int4 ii = idx4[n * 512 + t];
        ushort4 o;
        o.x = __bfloat16_as_ushort(xr[ii.x]);
        o.y = __bfloat16_as_ushort(xr[ii.y]);
        o.z = __bfloat16_as_ushort(xr[ii.z]);
        o.w = __bfloat16_as_ushort(xr[ii.w]);
        *(ushort4*)&g[((size_t)n * NB + b) * GG + t * 4] = o;
    }
}

// ---- fallback gather (half row in 64 KiB static LDS) ----
__global__ __launch_bounds__(512) void gather_half_k(const float* __restrict__ x,
                                                     const int* __restrict__ idx,
                                                     __hip_bfloat16* __restrict__ g) {
    __shared__ __align__(16) __hip_bfloat16 xr[32768];
    int b = blockIdx.x >> 1;
    int h = blockIdx.x & 1;
    int t = threadIdx.x;
    const float4* xv = (const float4*)(x + (size_t)b * DD + h * 32768);
#pragma unroll
    for (int i = 0; i < 16; ++i) {
        float4 v = xv[t + 512 * i];
        short4 p;
        p.x = (short)__bfloat16_as_ushort(__float2bfloat16(v.x));
        p.y = (short)__bfloat16_as_ushort(__float2bfloat16(v.y));
        p.z = (short)__bfloat16_as_ushort(__float2bfloat16(v.z));
        p.w = (short)__bfloat16_as_ushort(__float2bfloat16(v.w));
        *(short4*)&xr[(t + 512 * i) * 4] = p;
    }
    __syncthreads();
    const int4* idx4 = (const int4*)idx;
    for (int u = t; u < NN * GG / 4; u += 512) {
        int4 ii = idx4[u];
        int n = u >> 9;
        int k = (u & 511) * 4;
        __hip_bfloat16* dst = &g[((size_t)n * NB + b) * GG + k];
        if ((ii.x >> 15) == h) dst[0] = xr[ii.x & 32767];
        if ((ii.y >> 15) == h) dst[1] = xr[ii.y & 32767];
        if ((ii.z >> 15) == h) dst[2] = xr[ii.z & 32767];
        if ((ii.w >> 15) == h) dst[3] = xr[ii.w & 32767];
    }
}

// ---- GEMM1 split-K=4, double-buffered. grid 656 = 41n*2m*2o*4s;
// 256 thr = 4 waves, wave tile 64x64 (16 MFMA : 8 ds_read_b128);
// block tile 128x128, Kchunk 512, BK=32, 16 iters. bf16 partials.
__global__ __launch_bounds__(256) void gemm1_k(const __hip_bfloat16* __restrict__ g,
                                               const __hip_bfloat16* __restrict__ Wt,
                                               __hip_bfloat16* __restrict__ part1) {
    int bid = blockIdx.x;
    int s = bid & 3;
    int o0 = ((bid >> 2) & 1) * 128;
    int m0 = ((bid >> 3) & 1) * 128;
    int n = bid >> 4;
    const __hip_bfloat16* srcA = g + ((size_t)n * NB + m0) * GG + s * 512;
    const __hip_bfloat16* srcB = Wt + ((size_t)n * OO + o0) * GG + s * 512;
    __shared__ __align__(16) __hip_bfloat16 lA[2][128 * 32];
    __shared__ __align__(16) __hip_bfloat16 lB[2][128 * 32];
    int t = threadIdx.x;
    int lane = t & 63, w = t >> 6;
    int mw = (w >> 1) * 64, ow = (w & 1) * 64;
    int lrow = lane & 15, quad = lane >> 4;
    int r0 = t >> 2, q0 = (t & 3) * 8;  // staging: 2 chunks/thread/operand
    f32x4 acc[4][4] = {};

    gl_lds16(srcA + (size_t)r0 * GG + q0, &lA[0][t * 8]);
    gl_lds16(srcA + (size_t)(r0 + 64) * GG + q0, &lA[0][(t + 256) * 8]);
    gl_lds16(srcB + (size_t)r0 * GG + q0, &lB[0][t * 8]);
    gl_lds16(srcB + (size_t)(r0 + 64) * GG + q0, &lB[0][(t + 256) * 8]);
    __syncthreads();
#pragma unroll 1
    for (int it = 0; it < 16; ++it) {
        int cur = it & 1;
        if (it + 1 < 16) {
            int k1 = (it + 1) * 32;
            gl_lds16(srcA + (size_t)r0 * GG + k1 + q0, &lA[1 - cur][t * 8]);
            gl_lds16(srcA + (size_t)(r0 + 64) * GG + k1 + q0, &lA[1 - cur][(t + 256) * 8]);
            gl_lds16(srcB + (size_t)r0 * GG + k1 + q0, &lB[1 - cur][t * 8]);
            gl_lds16(srcB + (size_t)(r0 + 64) * GG + k1 + q0, &lB[1 - cur][(t + 256) * 8]);
        }
        bf16x8 af[4];
#pragma unroll
        for (int fm = 0; fm < 4; ++fm)
            af[fm] = *(const bf16x8*)&lA[cur][(mw + fm * 16 + lrow) * 32 + quad * 8];
#pragma unroll
        for (int fn = 0; fn < 4; ++fn) {
            bf16x8 bfr = *(const bf16x8*)&lB[cur][(ow + fn * 16 + lrow) * 32 + quad * 8];
#pragma unroll
            for (int fm = 0; fm < 4; ++fm)
                acc[fm][fn] = __builtin_amdgcn_mfma_f32_16x16x32_bf16(af[fm], bfr, acc[fm][fn], 0, 0, 0);
        }
        __syncthreads();  // safe to overwrite buf[cur] next iter; prefetch drained
    }
    // C/D layout: col=lane&15, row=quad*4+reg
#pragma unroll
    for (int fm = 0; fm < 4; ++fm) {
#pragma unroll
        for (int fn = 0; fn < 4; ++fn) {
            int col = o0 + ow + fn * 16 + lrow;
#pragma unroll
            for (int r = 0; r < 4; ++r) {
                int row = m0 + mw + fm * 16 + quad * 4 + r;
                part1[((size_t)s * NB + row) * NO + n * OO + col] = __float2bfloat16(acc[fm][fn][r]);
            }
        }
    }
}

// ---- combine 4 bf16 GEMM1 partials + bias -> h bf16 ----
__global__ __launch_bounds__(256) void combine1_k(const __hip_bfloat16* __restrict__ part1,
                                                  const float* __restrict__ bias,
                                                  __hip_bfloat16* __restrict__ h) {
    int j4 = blockIdx.x * 256 + threadIdx.x;  // 4-elem group over NB*NO/4
    int jj = j4 % (NO / 4);
    float4 a = ((const float4*)bias)[jj];
#pragma unroll
    for (int s = 0; s < 4; ++s) {
        ushort4 p = *(const ushort4*)&part1[(size_t)s * NB * NO + (size_t)j4 * 4];
        a.x += __bfloat162float(__ushort_as_bfloat16(p.x));
        a.y += __bfloat162float(__ushort_as_bfloat16(p.y));
        a.z += __bfloat162float(__ushort_as_bfloat16(p.z));
        a.w += __bfloat162float(__ushort_as_bfloat16(p.w));
    }
    ushort4 o;
    o.x = __bfloat16_as_ushort(__float2bfloat16(a.x));
    o.y = __bfloat16_as_ushort(__float2bfloat16(a.y));
    o.z = __bfloat16_as_ushort(__float2bfloat16(a.z));
    o.w = __bfloat16_as_ushort(__float2bfloat16(a.w));
    *(ushort4*)&h[(size_t)j4 * 4] = o;
}

// ---- GEMM2 split-K=41, double-buffered. grid 656 = 41s*2m*8e;
// 256 thr = 4 waves, wave tile 64x32; block 128x64, Kchunk 256, 8 iters.
__global__ __launch_bounds__(256) void gemm2_k(const __hip_bfloat16* __restrict__ h,
                                               const __hip_bfloat16* __restrict__ W3t,
                                               float* __restrict__ part) {
    int bid = blockIdx.x;
    int e0 = (bid & 7) * 64;
    int m0 = ((bid >> 3) & 1) * 128;
    int s = bid >> 4;  // 0..40
    const __hip_bfloat16* srcA = h + (size_t)m0 * NO + s * 256;
    const __hip_bfloat16* srcB = W3t + (size_t)e0 * NO + s * 256;
    __shared__ __align__(16) __hip_bfloat16 lA[2][128 * 32];
    __shared__ __align__(16) __hip_bfloat16 lB[2][64 * 32];
    int t = threadIdx.x;
    int lane = t & 63, w = t >> 6;
    int mw = (w >> 1) * 64, ew = (w & 1) * 32;
    int lrow = lane & 15, quad = lane >> 4;
    int rA = t >> 2, qA = (t & 3) * 8;   // A: 2 chunks/thread
    int rB = t >> 2, qB = (t & 3) * 8;   // B: 64 rows -> 1 chunk for t<256: r=t>>2 covers 0..63
    f32x4 acc[4][2] = {};

    gl_lds16(srcA + (size_t)rA * NO + qA, &lA[0][t * 8]);
    gl_lds16(srcA + (size_t)(rA + 64) * NO + qA, &lA[0][(t + 256) * 8]);
    gl_lds16(srcB + (size_t)(rB & 63) * NO + qB, &lB[0][t * 8]);
    __syncthreads();
#pragma unroll 1
    for (int it = 0; it < 8; ++it) {
        int cur = it & 1;
        if (it + 1 < 8) {
            int k1 = (it + 1) * 32;
            gl_lds16(srcA + (size_t)rA * NO + k1 + qA, &lA[1 - cur][t * 8]);
            gl_lds16(srcA + (size_t)(rA + 64) * NO + k1 + qA, &lA[1 - cur][(t + 256) * 8]);
            gl_lds16(srcB + (size_t)(rB & 63) * NO + k1 + qB, &lB[1 - cur][t * 8]);
        }
        bf16x8 af[4];
#pragma unroll
        for (int fm = 0; fm < 4; ++fm)
            af[fm] = *(const bf16x8*)&lA[cur][(mw + fm * 16 + lrow) * 32 + quad * 8];
#pragma unroll
        for (int fn = 0; fn < 2; ++fn) {
            bf16x8 bfr = *(const bf16x8*)&lB[cur][(ew + fn * 16 + lrow) * 32 + quad * 8];
#pragma unroll
            for (int fm = 0; fm < 4; ++fm)
                acc[fm][fn] = __builtin_amdgcn_mfma_f32_16x16x32_bf16(af[fm], bfr, acc[fm][fn], 0, 0, 0);
        }
        __syncthreads();
    }
#pragma unroll
    for (int fm = 0; fm < 4; ++fm) {
#pragma unroll
        for (int fn = 0; fn < 2; ++fn) {
            int e = e0 + ew + fn * 16 + lrow;
#pragma unroll
            for (int r = 0; r < 4; ++r) {
                int row = m0 + mw + fm * 16 + quad * 4 + r;
                part[((size_t)s * NB + row) * EE + e] = acc[fm][fn][r];
            }
        }
    }
}

// ---- reduce partials + bias + leaky relu ----
__global__ __launch_bounds__(256) void reduce_k(const float* __restrict__ part,
                                                const float* __restrict__ b3,
                                                float* __restrict__ out) {
    int j = blockIdx.x * 256 + threadIdx.x;  // float4 index over 256*512
    float4 a = make_float4(0.f, 0.f, 0.f, 0.f);
    for (int s = 0; s < NN; ++s) {
        float4 v = ((const float4*)part)[(size_t)s * (NB * EE / 4) + j];
        a.x += v.x; a.y += v.y; a.z += v.z; a.w += v.w;
    }
    float4 bv = ((const float4*)b3)[j & 127];
    a.x += bv.x; a.y += bv.y; a.z += bv.z; a.w += bv.w;
    a.x = a.x >= 0.f ? a.x : NEG_SLOPE * a.x;
    a.y = a.y >= 0.f ? a.y : NEG_SLOPE * a.y;
    a.z = a.z >= 0.f ? a.z : NEG_SLOPE * a.z;
    a.w = a.w >= 0.f ? a.w : NEG_SLOPE * a.w;
    ((float4*)out)[j] = a;
}

extern "C" void kernel_launch(void* const* d_in, const int* in_sizes, int n_in,
                              void* d_out, int out_size, void* d_ws, size_t ws_size,
                              hipStream_t stream) {
    const float* x = (const float*)d_in[0];
    const int* idx = (const int*)d_in[1];
    const float* W = (const float*)d_in[2];
    const float* bias = (const float*)d_in[3];
    const float* W3 = (const float*)d_in[4];
    const float* b3 = (const float*)d_in[5];
    float* out = (float*)d_out;

    char* ws = (char*)d_ws;
    const size_t g_off = 0;
    const size_t g_sz = (size_t)NN * NB * GG * 2;
    const size_t wt_off = g_off + g_sz;
    const size_t wt_sz = (size_t)NN * GG * OO * 2;
    const size_t w3t_off = wt_off + wt_sz;
    const size_t w3t_sz = (size_t)NO * EE * 2;
    const size_t h_off = w3t_off + w3t_sz;
    const size_t h_sz = (size_t)NB * NO * 2;
    const size_t p_off = h_off + h_sz;
    // part1 (4 bf16 planes = 21.5 MB) aliases part (41*NB*EE*4 = 21.5 MB):
    // part1 dead after combine1_k, before gemm2_k writes part.

    __hip_bfloat16* g = (__hip_bfloat16*)(ws + g_off);
    __hip_bfloat16* Wt = (__hip_bfloat16*)(ws + wt_off);
    __hip_bfloat16* W3t = (__hip_bfloat16*)(ws + w3t_off);
    __hip_bfloat16* h = (__hip_bfloat16*)(ws + h_off);
    __hip_bfloat16* part1 = (__hip_bfloat16*)(ws + p_off);
    float* part = (float*)(ws + p_off);

    // W (41,2048,256) -> Wt (41,256,2048) bf16
    transpose_cast_k<<<dim3(OO / 32, GG / 32, NN), 256, 0, stream>>>(W, Wt, GG, OO);
    // W3 (10496,512) -> W3t (512,10496) bf16
    transpose_cast_k<<<dim3(EE / 32, NO / 32, 1), 256, 0, stream>>>(W3, W3t, NO, EE);
    // gather: full 128 KiB row in dynamic LDS if allowed, else half-row fallback
    hipError_t aerr = hipFuncSetAttribute(reinterpret_cast<const void*>(gather_full_k),
                                          hipFuncAttributeMaxDynamicSharedMemorySize, 131072);
    if (aerr == hipSuccess) {
        gather_full_k<<<dim3(NB), 512, 131072, stream>>>(x, idx, g);
    } else {
        gather_half_k<<<dim3(512), 512, 0, stream>>>(x, idx, g);
    }
    // GEMM1 split-K=4, double-buffered, bf16 partials
    gemm1_k<<<dim3(656), 256, 0, stream>>>(g, Wt, part1);
    // combine 4 partials + bias -> h bf16
    combine1_k<<<dim3(NB * NO / 4 / 256), 256, 0, stream>>>(part1, bias, h);
    // GEMM2 split-K, double-buffered
    gemm2_k<<<dim3(656), 256, 0, stream>>>(h, W3t, part);
    // reduce + bias + leaky relu
    reduce_k<<<dim3(128), 256, 0, stream>>>(part, b3, out);
}